// Round 2
// baseline (252.131 us; speedup 1.0000x reference)
//
#include <hip/hip_runtime.h>
#include <hip/hip_bf16.h>

// Problem constants (SubClusteringNet): N=131072, K=16, IN=256, OUT=128
#define KEXP   16
#define IN_DIM 256
#define OUT_DIM 128
#define TILE   128   // tokens per mlp block

typedef float f32x4 __attribute__((ext_vector_type(4)));
typedef short bf16x8 __attribute__((ext_vector_type(8)));

__device__ __forceinline__ short f2bf(float f) {
    union { float f; unsigned u; } v; v.f = f;
    return (short)((v.u + 0x7fffu + ((v.u >> 16) & 1u)) >> 16);  // RNE
}

// ---------------- pass 1 (fused): W1 transpose->bf16  +  histogram of z ----------------
// blocks 0..127: tw1 (16 experts x 4 k-tiles x 2 n-tiles); blocks 128..383: hist
__global__ __launch_bounds__(256) void prep_k(const float* __restrict__ W1,
                                              ushort* __restrict__ w1t,
                                              const int* __restrict__ z,
                                              int* __restrict__ counts, int n) {
    __shared__ float ld[64][65];
    int bid = blockIdx.x, tid = threadIdx.x;
    if (bid < 128) {
        int e = bid >> 3, sub = bid & 7;
        int k0 = (sub & 3) * 64, n0 = (sub >> 2) * 64;
        const float* src = W1 + (long)e * (IN_DIM * OUT_DIM);   // [256][128]
        int tr = tid >> 6, tc = tid & 63;
#pragma unroll
        for (int i = 0; i < 16; i++) {
            int row = i * 4 + tr;
            ld[row][tc] = src[(k0 + row) * OUT_DIM + n0 + tc];
        }
        __syncthreads();
        ushort* dst = w1t + (long)e * (OUT_DIM * IN_DIM);       // [128][256]
#pragma unroll
        for (int i = 0; i < 16; i++) {
            int nrow = i * 4 + tr;
            dst[(n0 + nrow) * IN_DIM + k0 + tc] = (ushort)f2bf(ld[tc][nrow]);
        }
    } else {
        int* h = (int*)ld;
        if (tid < KEXP) h[tid] = 0;
        __syncthreads();
        for (int i = (bid - 128) * 256 + tid; i < n; i += 256 * 256)
            atomicAdd(&h[z[i]], 1);
        __syncthreads();
        if (tid < KEXP) atomicAdd(&counts[tid], h[tid]);
    }
}

// ---------------- pass 2: exclusive scan (tiny) ----------------
__global__ void scan_k(const int* __restrict__ counts, int* __restrict__ bases,
                       int* __restrict__ tb) {
    if (threadIdx.x == 0) {
        int acc = 0, tacc = 0;
        for (int i = 0; i < KEXP; i++) {
            bases[i] = acc;
            tb[i] = tacc;
            acc += counts[i];
            tacc += (counts[i] + TILE - 1) / TILE;
        }
        tb[KEXP] = tacc;
    }
}

// ---------------- pass 3: scatter perm (tokens grouped by expert) ----------------
__global__ __launch_bounds__(256) void scatter_k(const int* __restrict__ z,
                                                 const int* __restrict__ bases,
                                                 int* __restrict__ cursors,
                                                 int* __restrict__ perm, int n) {
    __shared__ int lc[KEXP];
    __shared__ int lb[KEXP];
    int tid = threadIdx.x;
    if (tid < KEXP) lc[tid] = 0;
    __syncthreads();
    int i = blockIdx.x * 256 + tid;
    int e = 0, r = 0;
    if (i < n) {
        e = z[i];
        r = atomicAdd(&lc[e], 1);
    }
    __syncthreads();
    if (tid < KEXP && lc[tid] > 0) lb[tid] = atomicAdd(&cursors[tid], lc[tid]);
    __syncthreads();
    if (i < n) perm[bases[e] + lb[e] + r] = i;
}

// ---------------- pass 4: grouped GEMM + fused MLP head + softmax ----------------
// 256 thr = 4 waves; 128 tokens x 128 outs per block; K=256 in one LDS stage.
// Wave wid owns tokens wid*32..wid*32+31 (two 16-row m-tiles sharing B-frags).
// LDS: full W1^T[e] [128 col][256 k] bf16 = 64 KB, XOR-swizzled (G4: 512B rows
// are 16-way conflicts unswizzled; byte ^= (col&7)<<4 makes reads <=2-way = free).
__global__ __launch_bounds__(256) void mlp_k(
    const float* __restrict__ x, const float* __restrict__ b1,
    const float* __restrict__ W2, const float* __restrict__ b2,
    const int* __restrict__ counts, const int* __restrict__ bases,
    const int* __restrict__ tb, const int* __restrict__ perm,
    const ushort* __restrict__ w1t, float* __restrict__ out) {
    __shared__ char smem[65536];
    int b = blockIdx.x;
    if (b >= tb[KEXP]) return;
    int e = 0;
#pragma unroll
    for (int i = 1; i < KEXP; i++)
        if (b >= tb[i]) e = i;
    int t = b - tb[e];
    int nrem = counts[e] - t * TILE;        // >= 1 for a live tile
    int pbase = bases[e] + t * TILE;

    int tid = threadIdx.x;
    int lane = tid & 63, wid = tid >> 6;
    int li = lane & 15, q = lane >> 4;

    // ---- issue all A-gather loads up front (32 x dwordx4 per wave, pure ILP) ----
    int m0 = wid * 32 + li;
    int m1 = wid * 32 + 16 + li;
    int g0 = perm[pbase + (m0 < nrem ? m0 : 0)];
    int g1 = perm[pbase + (m1 < nrem ? m1 : 0)];
    const float* xr0 = x + (long)g0 * IN_DIM;
    const float* xr1 = x + (long)g1 * IN_DIM;

    f32x4 a0[8][2], a1[8][2];
#pragma unroll
    for (int kk = 0; kk < 8; kk++) {
        int k0 = kk * 32 + q * 8;
        a0[kk][0] = *(const f32x4*)(xr0 + k0);
        a0[kk][1] = *(const f32x4*)(xr0 + k0 + 4);
        a1[kk][0] = *(const f32x4*)(xr1 + k0);
        a1[kk][1] = *(const f32x4*)(xr1 + k0 + 4);
    }

    // ---- stage W1^T[e] (64 KB) into LDS, swizzled; overlaps the A-load latency ----
    const char* wsrc = (const char*)(w1t + (long)e * (OUT_DIM * IN_DIM));
#pragma unroll
    for (int it = 0; it < 16; it++) {
        int byte = (it * 256 + tid) * 16;
        uint4 v = *(const uint4*)(wsrc + byte);
        int row = byte >> 9;                       // out-col index
        *(uint4*)(smem + (byte ^ ((row & 7) << 4))) = v;
    }
    __syncthreads();                               // the ONLY barrier

    // ---- convert A to bf16 fragments (data has arrived by now) ----
    bf16x8 af0[8], af1[8];
#pragma unroll
    for (int kk = 0; kk < 8; kk++) {
#pragma unroll
        for (int j = 0; j < 4; j++) {
            af0[kk][j]     = f2bf(a0[kk][0][j]);
            af0[kk][j + 4] = f2bf(a0[kk][1][j]);
            af1[kk][j]     = f2bf(a1[kk][0][j]);
            af1[kk][j + 4] = f2bf(a1[kk][1][j]);
        }
    }

    f32x4 acc0[8], acc1[8];
#pragma unroll
    for (int n = 0; n < 8; n++) { acc0[n] = (f32x4)0.0f; acc1[n] = (f32x4)0.0f; }

#pragma unroll
    for (int kk = 0; kk < 8; kk++) {
#pragma unroll
        for (int n = 0; n < 8; n++) {
            int col = n * 16 + li;
            int byte = col * 512 + kk * 64 + q * 16;
            bf16x8 bf = *(const bf16x8*)(smem + (byte ^ ((col & 7) << 4)));
            acc0[n] = __builtin_amdgcn_mfma_f32_16x16x32_bf16(af0[kk], bf, acc0[n], 0, 0, 0);
            acc1[n] = __builtin_amdgcn_mfma_f32_16x16x32_bf16(af1[kk], bf, acc1[n], 0, 0, 0);
        }
    }

    // ---- epilogue: relu + 128->2 head + softmax, 16-lane butterfly over li ----
    float p[2][2][4];
#pragma unroll
    for (int mt = 0; mt < 2; mt++)
#pragma unroll
        for (int l = 0; l < 2; l++)
#pragma unroll
            for (int r = 0; r < 4; r++) p[mt][l][r] = 0.0f;

#pragma unroll
    for (int n = 0; n < 8; n++) {
        int col = n * 16 + li;
        float bb = b1[e * OUT_DIM + col];
        float w0 = W2[e * OUT_DIM * 2 + col * 2 + 0];
        float w1 = W2[e * OUT_DIM * 2 + col * 2 + 1];
#pragma unroll
        for (int r = 0; r < 4; r++) {
            float h0 = fmaxf(acc0[n][r] + bb, 0.0f);
            float h1 = fmaxf(acc1[n][r] + bb, 0.0f);
            p[0][0][r] += h0 * w0;
            p[0][1][r] += h0 * w1;
            p[1][0][r] += h1 * w0;
            p[1][1][r] += h1 * w1;
        }
    }
#pragma unroll
    for (int m = 1; m < 16; m <<= 1)
#pragma unroll
        for (int mt = 0; mt < 2; mt++)
#pragma unroll
            for (int l = 0; l < 2; l++)
#pragma unroll
                for (int r = 0; r < 4; r++)
                    p[mt][l][r] += __shfl_xor(p[mt][l][r], m, 64);

    if (li == 0) {
        float bb0 = b2[e * 2], bb1 = b2[e * 2 + 1];
#pragma unroll
        for (int mt = 0; mt < 2; mt++)
#pragma unroll
            for (int r = 0; r < 4; r++) {
                int mm = wid * 32 + mt * 16 + q * 4 + r;
                if (mm < nrem) {
                    int orig = perm[pbase + mm];
                    float l0 = p[mt][0][r] + bb0, l1 = p[mt][1][r] + bb1;
                    float mx = fmaxf(l0, l1);
                    float e0 = __expf(l0 - mx), e1 = __expf(l1 - mx);
                    float inv = 1.0f / (e0 + e1);
                    *(float2*)(out + (long)orig * 2) = make_float2(e0 * inv, e1 * inv);
                }
            }
    }
}

extern "C" void kernel_launch(void* const* d_in, const int* in_sizes, int n_in,
                              void* d_out, int out_size, void* d_ws, size_t ws_size,
                              hipStream_t stream) {
    const float* x  = (const float*)d_in[0];
    const int*   z  = (const int*)d_in[1];
    const float* W1 = (const float*)d_in[2];
    const float* b1 = (const float*)d_in[3];
    const float* W2 = (const float*)d_in[4];
    const float* b2 = (const float*)d_in[5];
    float* out = (float*)d_out;
    int n = in_sizes[1];                    // 131072 tokens

    // ws layout: [counts 16][cursors 16][bases 16][tb 17] ... perm[n] @1024 ... w1t bf16
    int* counts  = (int*)d_ws;
    int* cursors = counts + 16;
    int* basesp  = counts + 32;
    int* tbp     = counts + 48;
    int* perm    = counts + 256;                                  // byte offset 1024
    ushort* w1t  = (ushort*)((char*)d_ws + 1024 + (size_t)n * 4); // 16B-aligned

    hipMemsetAsync(counts, 0, 128, stream);                       // counts + cursors
    prep_k<<<384, 256, 0, stream>>>(W1, w1t, z, counts, n);
    scan_k<<<1, 64, 0, stream>>>(counts, basesp, tbp);
    scatter_k<<<(n + 255) / 256, 256, 0, stream>>>(z, basesp, cursors, perm, n);

    int maxtiles = (n + TILE - 1) / TILE + (KEXP - 1);
    mlp_k<<<maxtiles, 256, 0, stream>>>(x, b1, W2, b2, counts, basesp, tbp, perm, w1t, out);
}

// Round 3
// 228.715 us; speedup vs baseline: 1.1024x; 1.1024x over previous
//
#include <hip/hip_runtime.h>
#include <hip/hip_bf16.h>

// SubClusteringNet: N=131072, K=16, IN=256, OUT=128
#define KEXP   16
#define IN_DIM 256
#define OUT_DIM 128
#define TILE   128        // tokens per tile
#define BPE    16         // persistent blocks per expert (16*16 = 256 = #CUs)

typedef float f32x4 __attribute__((ext_vector_type(4)));
typedef short bf16x8 __attribute__((ext_vector_type(8)));
typedef const unsigned int __attribute__((address_space(1)))* gptr_t;
typedef unsigned int __attribute__((address_space(3)))* lptr_t;

__device__ __forceinline__ ushort f2bf(float f) {
    union { float f; unsigned u; } v; v.f = f;
    return (ushort)((v.u + 0x7fffu + ((v.u >> 16) & 1u)) >> 16);  // RNE
}

// ---------------- pass 1 (fused): W1 transpose->bf16 (pre-swizzled)  +  histogram ----------------
// blocks 0..127: tw1; blocks 128..383: hist
// w1t logical layout [K][128 outcol][256 k] bf16; stored byte S = L ^ ((outcol&7)<<4)
// so that mlp's LINEAR global_load_lds puts it in LDS already swizzled (G4 fix).
__global__ __launch_bounds__(256) void prep_k(const float* __restrict__ W1,
                                              ushort* __restrict__ w1t,
                                              const int* __restrict__ z,
                                              int* __restrict__ counts, int n) {
    __shared__ float ld[64][65];
    int bid = blockIdx.x, tid = threadIdx.x;
    if (bid < 128) {
        int e = bid >> 3, sub = bid & 7;
        int k0 = (sub & 3) * 64, n0 = (sub >> 2) * 64;
        const float* src = W1 + (long)e * (IN_DIM * OUT_DIM);   // [256][128]
        int tr = tid >> 6, tc = tid & 63;
#pragma unroll
        for (int i = 0; i < 16; i++) {
            int row = i * 4 + tr;
            ld[row][tc] = src[(k0 + row) * OUT_DIM + n0 + tc];
        }
        __syncthreads();
        char* dst = (char*)w1t + (long)e * (OUT_DIM * IN_DIM * 2);
#pragma unroll
        for (int i = 0; i < 16; i++) {
            int col = n0 + i * 4 + tr;                      // out col
            int L = (col * IN_DIM + k0 + tc) * 2;           // logical byte
            int S = L ^ ((col & 7) << 4);                   // swizzled store
            *(ushort*)(dst + S) = f2bf(ld[tc][i * 4 + tr]);
        }
    } else {
        int* h = (int*)ld;
        if (tid < KEXP) h[tid] = 0;
        __syncthreads();
        for (int i = (bid - 128) * 256 + tid; i < n; i += 256 * 256)
            atomicAdd(&h[z[i]], 1);
        __syncthreads();
        if (tid < KEXP) atomicAdd(&counts[tid], h[tid]);
    }
}

// ---------------- pass 2: exclusive scan (tiny) ----------------
__global__ void scan_k(const int* __restrict__ counts, int* __restrict__ bases) {
    if (threadIdx.x == 0) {
        int acc = 0;
        for (int i = 0; i < KEXP; i++) { bases[i] = acc; acc += counts[i]; }
    }
}

// ---------------- pass 3: scatter perm (tokens grouped by expert) ----------------
__global__ __launch_bounds__(256) void scatter_k(const int* __restrict__ z,
                                                 const int* __restrict__ bases,
                                                 int* __restrict__ cursors,
                                                 int* __restrict__ perm, int n) {
    __shared__ int lc[KEXP];
    __shared__ int lb[KEXP];
    int tid = threadIdx.x;
    if (tid < KEXP) lc[tid] = 0;
    __syncthreads();
    int i = blockIdx.x * 256 + tid;
    int e = 0, r = 0;
    if (i < n) {
        e = z[i];
        r = atomicAdd(&lc[e], 1);
    }
    __syncthreads();
    if (tid < KEXP && lc[tid] > 0) lb[tid] = atomicAdd(&cursors[tid], lc[tid]);
    __syncthreads();
    if (i < n) perm[bases[e] + lb[e] + r] = i;
}

// ---------------- pass 4: persistent grouped GEMM + fused head + softmax ----------------
// 256 blocks (1/CU), 512 thr = 8 waves. Block b serves expert b>>4, tile slots (b&15)+16j.
// LDS: W1^T[e] 64 KB (swizzled, staged ONCE via linear global_load_lds from pre-swizzled
// w1t) + A-tile [128 tok][256 k] bf16 64 KB (coalesced f32 row loads -> cvt -> swizzled
// ds_write). Wave w owns m-tile w (16 tokens) x full 128 outs: 8kk x 8n MFMA.
// Next tile's A-loads are issued BEFORE compute of the current tile (T14).
__global__ __launch_bounds__(512, 2) void mlp_k(
    const float* __restrict__ x, const float* __restrict__ b1,
    const float* __restrict__ W2, const float* __restrict__ b2,
    const int* __restrict__ counts, const int* __restrict__ bases,
    const int* __restrict__ perm, const ushort* __restrict__ w1t,
    float* __restrict__ out) {
    __shared__ char Wl[65536];
    __shared__ char Al[65536];

    int b = blockIdx.x;
    int e = b >> 4, slot = b & 15;
    int cnt = counts[e];
    int pb0 = bases[e];
    int ntiles = (cnt + TILE - 1) / TILE;

    int tid = threadIdx.x;
    int lane = tid & 63, w = tid >> 6;
    int li = lane & 15, q = lane >> 4;

    // ---- stage W (64 KB) once: 8 x 1KB linear global_load_lds per wave ----
    const char* wsrc = (const char*)w1t + (long)e * (OUT_DIM * IN_DIM * 2);
#pragma unroll
    for (int i = 0; i < 8; i++) {
        int off = w * 8192 + i * 1024;
        __builtin_amdgcn_global_load_lds((gptr_t)(wsrc + off + lane * 16),
                                         (lptr_t)(Wl + off), 16, 0, 0);
    }
    // completion covered by the first __syncthreads below (drains vmcnt)

    // ---- hoist epilogue constants (expert-fixed) ----
    float bbv[8], w2a[8], w2b[8];
#pragma unroll
    for (int nn = 0; nn < 8; nn++) {
        int col = nn * 16 + li;
        bbv[nn] = b1[e * OUT_DIM + col];
        w2a[nn] = W2[(e * OUT_DIM + col) * 2 + 0];
        w2b[nn] = W2[(e * OUT_DIM + col) * 2 + 1];
    }
    float bb0 = b2[e * 2 + 0], bb1 = b2[e * 2 + 1];

    // ---- prologue: issue A loads for first tile (coalesced: 1 instr = 1 full row) ----
    f32x4 av[16];
    int pb_cur = 0, nr_cur = 0;
    if (slot < ntiles) {
        pb_cur = pb0 + slot * TILE;
        nr_cur = cnt - slot * TILE;
        int rr = w * 16 + li;
        int pv = perm[pb_cur + (rr < nr_cur ? rr : nr_cur - 1)];
#pragma unroll
        for (int i = 0; i < 16; i++) {
            int g = __shfl(pv, i, 16);
            av[i] = *(const f32x4*)((const char*)x + (long)g * 1024 + lane * 16);
        }
    }

    for (int t = slot; t < ntiles; t += BPE) {
        // ---- cvt + swizzled ds_write of current A tile ----
#pragma unroll
        for (int i = 0; i < 16; i++) {
            int r = w * 16 + i;
            uint2 pk;
            pk.x = (unsigned)f2bf(av[i][0]) | ((unsigned)f2bf(av[i][1]) << 16);
            pk.y = (unsigned)f2bf(av[i][2]) | ((unsigned)f2bf(av[i][3]) << 16);
            *(uint2*)(Al + r * 512 + ((lane * 8) ^ ((r & 7) << 4))) = pk;
        }
        __syncthreads();   // A (and W on first iter) visible to all waves

        // ---- issue NEXT tile's A loads (hidden under compute) ----
        int tn = t + BPE;
        int pb_nx = 0, nr_nx = 0;
        if (tn < ntiles) {
            pb_nx = pb0 + tn * TILE;
            nr_nx = cnt - tn * TILE;
            int rr = w * 16 + li;
            int pv = perm[pb_nx + (rr < nr_nx ? rr : nr_nx - 1)];
#pragma unroll
            for (int i = 0; i < 16; i++) {
                int g = __shfl(pv, i, 16);
                av[i] = *(const f32x4*)((const char*)x + (long)g * 1024 + lane * 16);
            }
        }

        // ---- compute: wave w = m-tile w; 8 kk x 8 n MFMA ----
        f32x4 acc[8];
#pragma unroll
        for (int nn = 0; nn < 8; nn++) acc[nn] = (f32x4)0.0f;

        int arow = w * 16 + li;
        int aswz = (arow & 7) << 4;
#pragma unroll
        for (int kk = 0; kk < 8; kk++) {
            bf16x8 af = *(const bf16x8*)(Al + arow * 512 + ((kk * 64 + q * 16) ^ aswz));
#pragma unroll
            for (int nn = 0; nn < 8; nn++) {
                int col = nn * 16 + li;
                bf16x8 bf = *(const bf16x8*)(Wl + col * 512 + ((kk * 64 + q * 16) ^ ((col & 7) << 4)));
                acc[nn] = __builtin_amdgcn_mfma_f32_16x16x32_bf16(af, bf, acc[nn], 0, 0, 0);
            }
        }

        // ---- epilogue: relu + 128->2 head + softmax; 16-lane butterfly over li ----
        float p0[4] = {0.f, 0.f, 0.f, 0.f}, p1[4] = {0.f, 0.f, 0.f, 0.f};
#pragma unroll
        for (int nn = 0; nn < 8; nn++) {
#pragma unroll
            for (int r = 0; r < 4; r++) {
                float h = fmaxf(acc[nn][r] + bbv[nn], 0.0f);
                p0[r] += h * w2a[nn];
                p1[r] += h * w2b[nn];
            }
        }
#pragma unroll
        for (int m = 1; m < 16; m <<= 1)
#pragma unroll
            for (int r = 0; r < 4; r++) {
                p0[r] += __shfl_xor(p0[r], m, 64);
                p1[r] += __shfl_xor(p1[r], m, 64);
            }
        if (li == 0) {
#pragma unroll
            for (int r = 0; r < 4; r++) {
                int mm = w * 16 + q * 4 + r;
                if (mm < nr_cur) {
                    int orig = perm[pb_cur + mm];
                    float l0 = p0[r] + bb0, l1 = p1[r] + bb1;
                    float mx = fmaxf(l0, l1);
                    float e0 = __expf(l0 - mx), e1 = __expf(l1 - mx);
                    float inv = 1.0f / (e0 + e1);
                    *(float2*)(out + (long)orig * 2) = make_float2(e0 * inv, e1 * inv);
                }
            }
        }
        __syncthreads();   // all reads of Al done before next iter's overwrite
        pb_cur = pb_nx;
        nr_cur = nr_nx;
    }
}

extern "C" void kernel_launch(void* const* d_in, const int* in_sizes, int n_in,
                              void* d_out, int out_size, void* d_ws, size_t ws_size,
                              hipStream_t stream) {
    const float* x  = (const float*)d_in[0];
    const int*   z  = (const int*)d_in[1];
    const float* W1 = (const float*)d_in[2];
    const float* b1 = (const float*)d_in[3];
    const float* W2 = (const float*)d_in[4];
    const float* b2 = (const float*)d_in[5];
    float* out = (float*)d_out;
    int n = in_sizes[1];                    // 131072 tokens

    // ws layout: [counts 16][cursors 16][bases 16][pad] perm[n] @1024 ... w1t bf16
    int* counts  = (int*)d_ws;
    int* cursors = counts + 16;
    int* basesp  = counts + 32;
    int* perm    = counts + 256;                                  // byte offset 1024
    ushort* w1t  = (ushort*)((char*)d_ws + 1024 + (size_t)n * 4); // 16B-aligned

    hipMemsetAsync(counts, 0, 128, stream);                       // counts + cursors
    prep_k<<<384, 256, 0, stream>>>(W1, w1t, z, counts, n);
    scan_k<<<1, 64, 0, stream>>>(counts, basesp);
    scatter_k<<<(n + 255) / 256, 256, 0, stream>>>(z, basesp, cursors, perm, n);
    mlp_k<<<KEXP * BPE, 512, 0, stream>>>(x, b1, W2, b2, counts, basesp, perm, w1t, out);
}

// Round 4
// 224.352 us; speedup vs baseline: 1.1238x; 1.0194x over previous
//
#include <hip/hip_runtime.h>
#include <hip/hip_bf16.h>

// SubClusteringNet: N=131072, K=16, IN=256, OUT=128
#define KEXP   16
#define IN_DIM 256
#define OUT_DIM 128
#define TILE   128        // tokens per tile
#define BPE    16         // persistent blocks per expert (16*16 = 256 = #CUs)

typedef float f32x4 __attribute__((ext_vector_type(4)));
typedef short bf16x8 __attribute__((ext_vector_type(8)));
typedef const unsigned int __attribute__((address_space(1)))* gptr_t;
typedef unsigned int __attribute__((address_space(3)))* lptr_t;

__device__ __forceinline__ ushort f2bf(float f) {
    union { float f; unsigned u; } v; v.f = f;
    return (ushort)((v.u + 0x7fffu + ((v.u >> 16) & 1u)) >> 16);  // RNE
}

// ---------------- pass 1 (fused): W1 transpose->bf16 (pre-swizzled)  +  histogram ----------------
// blocks 0..127: tw1; blocks 128..383: hist
// w1t logical layout [K][128 outcol][256 k] bf16; stored byte S = L ^ ((outcol&7)<<4)
// so mlp's LINEAR global_load_lds lands it in LDS already swizzled (G4 fix, m173 pattern).
__global__ __launch_bounds__(256) void prep_k(const float* __restrict__ W1,
                                              ushort* __restrict__ w1t,
                                              const int* __restrict__ z,
                                              int* __restrict__ counts, int n) {
    __shared__ float ld[64][65];
    int bid = blockIdx.x, tid = threadIdx.x;
    if (bid < 128) {
        int e = bid >> 3, sub = bid & 7;
        int k0 = (sub & 3) * 64, n0 = (sub >> 2) * 64;
        const float* src = W1 + (long)e * (IN_DIM * OUT_DIM);   // [256][128]
        int tr = tid >> 6, tc = tid & 63;
#pragma unroll
        for (int i = 0; i < 16; i++) {
            int row = i * 4 + tr;
            ld[row][tc] = src[(k0 + row) * OUT_DIM + n0 + tc];
        }
        __syncthreads();
        char* dst = (char*)w1t + (long)e * (OUT_DIM * IN_DIM * 2);
#pragma unroll
        for (int i = 0; i < 16; i++) {
            int col = n0 + i * 4 + tr;                      // out col
            int L = (col * IN_DIM + k0 + tc) * 2;           // logical byte
            int S = L ^ ((col & 7) << 4);                   // swizzled store
            *(ushort*)(dst + S) = f2bf(ld[tc][i * 4 + tr]);
        }
    } else {
        int* h = (int*)ld;
        if (tid < KEXP) h[tid] = 0;
        __syncthreads();
        for (int i = (bid - 128) * 256 + tid; i < n; i += 256 * 256)
            atomicAdd(&h[z[i]], 1);
        __syncthreads();
        if (tid < KEXP) atomicAdd(&counts[tid], h[tid]);
    }
}

// ---------------- pass 2: exclusive scan, 16-lane parallel (was 1-thread serial) ----------------
__global__ void scan_k(const int* __restrict__ counts, int* __restrict__ bases) {
    int li = threadIdx.x & 63;
    int c = (li < KEXP) ? counts[li] : 0;
    int v = c;
#pragma unroll
    for (int d = 1; d < KEXP; d <<= 1) {
        int t = __shfl_up(v, d, 64);
        if (li >= d) v += t;
    }
    if (li < KEXP) bases[li] = v - c;
}

// ---------------- pass 3: scatter perm; 128 blocks, 4 tok/thread (4x fewer global atomics) ----
__global__ __launch_bounds__(256) void scatter_k(const int* __restrict__ z,
                                                 const int* __restrict__ bases,
                                                 int* __restrict__ cursors,
                                                 int* __restrict__ perm, int n) {
    __shared__ int lc[KEXP];
    __shared__ int lb[KEXP];
    int tid = threadIdx.x;
    if (tid < KEXP) lc[tid] = 0;
    __syncthreads();
    int base = blockIdx.x * 1024 + tid;
    int e[4], r[4];
#pragma unroll
    for (int j = 0; j < 4; j++) {
        int i = base + j * 256;
        if (i < n) {
            e[j] = z[i];
            r[j] = atomicAdd(&lc[e[j]], 1);
        } else e[j] = -1;
    }
    __syncthreads();
    if (tid < KEXP && lc[tid] > 0) lb[tid] = atomicAdd(&cursors[tid], lc[tid]);
    __syncthreads();
#pragma unroll
    for (int j = 0; j < 4; j++) {
        int i = base + j * 256;
        if (i < n) perm[bases[e[j]] + lb[e[j]] + r[j]] = i;
    }
}

// ---------------- pass 4: persistent grouped GEMM + fused head + softmax ----------------
// 256 blocks (1/CU), 512 thr = 8 waves. Block b: expert b>>4, tile slots (b&15)+16j.
// LDS: W 64 KB (staged once, pre-swizzled global -> linear gll) + A 64 KB.
// Pipeline per tile: ds_write A(pk) | sync | issue next A loads | compute (loads hide
// under ~7k cy of ds_read+MFMA) | epilogue | cvt av->pk | sync.
// __launch_bounds__(512,1): LDS already caps at 1 block/CU (2 waves/SIMD), so allow
// the full 256-VGPR budget -> no scratch spills (the R2/R3 killer).
__global__ __launch_bounds__(512, 1) void mlp_k(
    const float* __restrict__ x, const float* __restrict__ b1,
    const float* __restrict__ W2, const float* __restrict__ b2,
    const int* __restrict__ counts, const int* __restrict__ bases,
    const int* __restrict__ perm, const ushort* __restrict__ w1t,
    float* __restrict__ out) {
    __shared__ char Wl[65536];
    __shared__ char Al[65536];

    int b = blockIdx.x;
    int e = b >> 4, slot = b & 15;
    int cnt = counts[e];
    int pb0 = bases[e];
    int ntiles = (cnt + TILE - 1) / TILE;

    int tid = threadIdx.x;
    int lane = tid & 63, w = tid >> 6;
    int li = lane & 15, q = lane >> 4;

    // ---- stage W (64 KB) once: 8 x 1KB linear global_load_lds per wave ----
    const char* wsrc = (const char*)w1t + (long)e * (OUT_DIM * IN_DIM * 2);
#pragma unroll
    for (int i = 0; i < 8; i++) {
        int off = w * 8192 + i * 1024;
        __builtin_amdgcn_global_load_lds((gptr_t)(wsrc + off + lane * 16),
                                         (lptr_t)(Wl + off), 16, 0, 0);
    }
    // completion covered by the first __syncthreads (vmcnt drain)

    // ---- hoist epilogue constants (expert-fixed) ----
    float bbv[8], w2a[8], w2b[8];
#pragma unroll
    for (int nn = 0; nn < 8; nn++) {
        int col = nn * 16 + li;
        bbv[nn] = b1[e * OUT_DIM + col];
        w2a[nn] = W2[(e * OUT_DIM + col) * 2 + 0];
        w2b[nn] = W2[(e * OUT_DIM + col) * 2 + 1];
    }
    float bb0 = b2[e * 2 + 0], bb1 = b2[e * 2 + 1];

    // ---- prologue: load + pack first tile ----
    uint2 pk[16];
    int pb_cur = 0, nr_cur = 0;
    if (slot < ntiles) {
        pb_cur = pb0 + slot * TILE;
        nr_cur = cnt - slot * TILE;
        int rr = w * 16 + li;
        int pv = perm[pb_cur + (rr < nr_cur ? rr : nr_cur - 1)];
        f32x4 av[16];
#pragma unroll
        for (int i = 0; i < 16; i++) {
            int g = __shfl(pv, i, 16);
            av[i] = *(const f32x4*)((const char*)x + (long)g * 1024 + lane * 16);
        }
#pragma unroll
        for (int i = 0; i < 16; i++) {
            pk[i].x = (unsigned)f2bf(av[i][0]) | ((unsigned)f2bf(av[i][1]) << 16);
            pk[i].y = (unsigned)f2bf(av[i][2]) | ((unsigned)f2bf(av[i][3]) << 16);
        }
    }

    for (int t = slot; t < ntiles; t += BPE) {
        // ---- swizzled ds_write of current A tile (from packed regs) ----
#pragma unroll
        for (int i = 0; i < 16; i++) {
            int r = w * 16 + i;
            *(uint2*)(Al + r * 512 + ((lane * 8) ^ ((r & 7) << 4))) = pk[i];
        }
        __syncthreads();   // A (and W on first iter) visible to all waves

        // ---- issue NEXT tile's A loads (f32, convert deferred past compute) ----
        int tn = t + BPE;
        int pb_nx = 0, nr_nx = 0;
        f32x4 av[16];
        bool have_nx = (tn < ntiles);
        if (have_nx) {
            pb_nx = pb0 + tn * TILE;
            nr_nx = cnt - tn * TILE;
            int rr = w * 16 + li;
            int pv = perm[pb_nx + (rr < nr_nx ? rr : nr_nx - 1)];
#pragma unroll
            for (int i = 0; i < 16; i++) {
                int g = __shfl(pv, i, 16);
                av[i] = *(const f32x4*)((const char*)x + (long)g * 1024 + lane * 16);
            }
        }

        // ---- compute: wave w = m-tile w (16 tokens) x 128 cols; 8 kk x 8 nn MFMA ----
        f32x4 acc[8];
#pragma unroll
        for (int nn = 0; nn < 8; nn++) acc[nn] = (f32x4)0.0f;

        int arow = w * 16 + li;
        int aswz = (arow & 7) << 4;
#pragma unroll
        for (int kk = 0; kk < 8; kk++) {
            bf16x8 af = *(const bf16x8*)(Al + arow * 512 + ((kk * 64 + q * 16) ^ aswz));
#pragma unroll
            for (int nn = 0; nn < 8; nn++) {
                int col = nn * 16 + li;
                bf16x8 bf = *(const bf16x8*)(Wl + col * 512 + ((kk * 64 + q * 16) ^ ((col & 7) << 4)));
                acc[nn] = __builtin_amdgcn_mfma_f32_16x16x32_bf16(af, bf, acc[nn], 0, 0, 0);
            }
        }

        // ---- epilogue: relu + 128->2 head + softmax; 16-lane butterfly over li ----
        float p0[4] = {0.f, 0.f, 0.f, 0.f}, p1[4] = {0.f, 0.f, 0.f, 0.f};
#pragma unroll
        for (int nn = 0; nn < 8; nn++) {
#pragma unroll
            for (int r = 0; r < 4; r++) {
                float h = fmaxf(acc[nn][r] + bbv[nn], 0.0f);
                p0[r] += h * w2a[nn];
                p1[r] += h * w2b[nn];
            }
        }
#pragma unroll
        for (int m = 1; m < 16; m <<= 1)
#pragma unroll
            for (int r = 0; r < 4; r++) {
                p0[r] += __shfl_xor(p0[r], m, 64);
                p1[r] += __shfl_xor(p1[r], m, 64);
            }
        if (li == 0) {
#pragma unroll
            for (int r = 0; r < 4; r++) {
                int mm = w * 16 + q * 4 + r;
                if (mm < nr_cur) {
                    int orig = perm[pb_cur + mm];
                    float l0 = p0[r] + bb0, l1 = p1[r] + bb1;
                    float mx = fmaxf(l0, l1);
                    float e0 = __expf(l0 - mx), e1 = __expf(l1 - mx);
                    float inv = 1.0f / (e0 + e1);
                    *(float2*)(out + (long)orig * 2) = make_float2(e0 * inv, e1 * inv);
                }
            }
        }

        // ---- convert next tile to bf16 (loads have arrived during compute) ----
        if (have_nx) {
#pragma unroll
            for (int i = 0; i < 16; i++) {
                pk[i].x = (unsigned)f2bf(av[i][0]) | ((unsigned)f2bf(av[i][1]) << 16);
                pk[i].y = (unsigned)f2bf(av[i][2]) | ((unsigned)f2bf(av[i][3]) << 16);
            }
        }
        __syncthreads();   // all reads of Al done before next iter's overwrite
        pb_cur = pb_nx;
        nr_cur = nr_nx;
    }
}

extern "C" void kernel_launch(void* const* d_in, const int* in_sizes, int n_in,
                              void* d_out, int out_size, void* d_ws, size_t ws_size,
                              hipStream_t stream) {
    const float* x  = (const float*)d_in[0];
    const int*   z  = (const int*)d_in[1];
    const float* W1 = (const float*)d_in[2];
    const float* b1 = (const float*)d_in[3];
    const float* W2 = (const float*)d_in[4];
    const float* b2 = (const float*)d_in[5];
    float* out = (float*)d_out;
    int n = in_sizes[1];                    // 131072 tokens

    // ws layout: [counts 16][cursors 16][bases 16][pad] perm[n] @1024 ... w1t bf16
    int* counts  = (int*)d_ws;
    int* cursors = counts + 16;
    int* basesp  = counts + 32;
    int* perm    = counts + 256;                                  // byte offset 1024
    ushort* w1t  = (ushort*)((char*)d_ws + 1024 + (size_t)n * 4); // 16B-aligned

    hipMemsetAsync(counts, 0, 128, stream);                       // counts + cursors
    prep_k<<<384, 256, 0, stream>>>(W1, w1t, z, counts, n);
    scan_k<<<1, 64, 0, stream>>>(counts, basesp);
    scatter_k<<<(n + 1023) / 1024, 256, 0, stream>>>(z, basesp, cursors, perm, n);
    mlp_k<<<KEXP * BPE, 512, 0, stream>>>(x, b1, W2, b2, counts, basesp, perm, w1t, out);
}